// Round 15
// baseline (3071.560 us; speedup 1.0000x reference)
//
#include <hip/hip_runtime.h>
#include <cstdint>
#include <cstddef>

#define S_LEN 256
#define BATCH 64
#define HID   1024
#define GATES 4096
#define NBLK  256
#define RING_D 4         // h0 ring depth
#define FLAG_STRIDE 32   // 32 uints = 128 B: one cache line per flag

typedef _Float16 h16;
typedef _Float16 h16x8 __attribute__((ext_vector_type(8)));
typedef _Float16 h16x4 __attribute__((ext_vector_type(4)));
typedef float    f32x4 __attribute__((ext_vector_type(4)));

// ---------------------------------------------------------------------------
// x fp32 -> fp16 (one pass)
// ---------------------------------------------------------------------------
__global__ __launch_bounds__(256)
void xconv_kernel(const float* __restrict__ x, h16* __restrict__ x16)
{
  const int n4 = S_LEN * BATCH * HID / 4;
  const int stride = gridDim.x * 256;
  for (int i = blockIdx.x * 256 + threadIdx.x; i < n4; i += stride) {
    f32x4 v = ((const f32x4*)x)[i];
    h16x4 o;
    o[0] = (h16)v[0]; o[1] = (h16)v[1]; o[2] = (h16)v[2]; o[3] = (h16)v[3];
    ((h16x4*)x16)[i] = o;
  }
}

// ---------------------------------------------------------------------------
// Device-scope (sc1) 16B load: bypasses L1+L2, reads L3 coherence point.
// Issued without internal wait so batches pipeline; caller fences with
// vmcnt(0) + sched_barrier(0) before use (rule-18).
// ---------------------------------------------------------------------------
#define RLOAD(dst, ptr, OFFSTR)                                         \
  asm volatile("global_load_dwordx4 %0, %1, off offset:" OFFSTR " sc1"  \
               : "=&v"(dst) : "v"(ptr) : "memory")

// ---------------------------------------------------------------------------
// Merged in-wave poll: lane watches 2 own-group flags and 2 other-group
// flags; single loop -> ONE L3 round trip in steady state instead of two
// serialized polls. tgt==0 auto-passes (flags are unsigned).
// ---------------------------------------------------------------------------
__device__ __forceinline__ void wave_poll_dual(const unsigned* flags,
                                               int own_base, unsigned to,
                                               int oth_base, unsigned tx,
                                               int lane)
{
  const unsigned* a0 = &flags[(size_t)(own_base + lane) * FLAG_STRIDE];
  const unsigned* a1 = &flags[(size_t)(own_base + 64 + lane) * FLAG_STRIDE];
  const unsigned* b0 = &flags[(size_t)(oth_base + lane) * FLAG_STRIDE];
  const unsigned* b1 = &flags[(size_t)(oth_base + 64 + lane) * FLAG_STRIDE];
  while (__hip_atomic_load(a0, __ATOMIC_RELAXED, __HIP_MEMORY_SCOPE_AGENT) < to ||
         __hip_atomic_load(a1, __ATOMIC_RELAXED, __HIP_MEMORY_SCOPE_AGENT) < to ||
         __hip_atomic_load(b0, __ATOMIC_RELAXED, __HIP_MEMORY_SCOPE_AGENT) < tx ||
         __hip_atomic_load(b1, __ATOMIC_RELAXED, __HIP_MEMORY_SCOPE_AGENT) < tx)
    __builtin_amdgcn_s_sleep(1);
}

// ---------------------------------------------------------------------------
// Persistent 2-layer decoupled-pipeline LSTM, single-wait single-burst step.
// 256 WGs x 512 thr. Group 0 = blocks 0..127 (layer 0), group 1 = layer 1.
// Per iteration t (one serialized wait, one load burst, straight-line math):
//   WAIT   : in-wave merged poll:
//              L0: own >= t            and L1 >= t+1-RING_D (slot safety)
//              L1: own >= t            and L0 >= t+1        (h0[t] ready)
//   LOADS  : input-part A (x16[t] plain / h0[t] sc1) AND hidden-part A
//            (h_own[t-1] sc1) issued as one 32x16B burst, single vmcnt(0).
//   COMPUTE: 64 MFMA (K=2048 total; per-wave K-slice 128 input + 128 hidden).
//   REDUCE : 2-round 8-way LDS reduce (32KB plds), activations, sc1 h
//            stores, publish flag t+1.
// LDS: 128KB weights + 32KB plds = exactly 160 KiB.
// No cache maintenance anywhere: mutable data all-sc1, immutable plain.
// ---------------------------------------------------------------------------
__global__ __launch_bounds__(512, 1)
void lstm_persistent(const h16* __restrict__ x16,
                     const float* __restrict__ weight,
                     const float* __restrict__ bias,
                     h16* __restrict__ h0r,
                     h16* __restrict__ h1r,
                     unsigned* __restrict__ flags)
{
  __shared__ h16   wlds[65536];          // 128 KB
  __shared__ float plds[2][8][16][32];   // 32 KB

  const int wg    = blockIdx.x;
  const int layer = wg >> 7;
  const int j0    = (wg & 127) * 8;
  const int tid   = threadIdx.x;
  const int wave  = tid >> 6, lane = tid & 63;
  const int l15   = lane & 15, l16 = lane >> 4;
  const int BH    = BATCH * HID;

  // ---- one-time: pack weights fp32->fp16 into LDS ----
  // c = (((part*8 + w)*2 + n2)*4 + s)*64 + ln
  {
    const float* wsrc = weight + (size_t)layer * 2 * GATES * HID;
    for (int c = tid; c < 8192; c += 512) {
      const int ln = c & 63, s = (c >> 6) & 3, n2 = (c >> 8) & 1,
                w = (c >> 9) & 7, part = c >> 12;
      const int lc  = n2 * 16 + (ln & 15);              // local col 0..31
      const int col = (lc >> 3) * HID + j0 + (lc & 7);  // global gate col
      const int k   = w * 128 + s * 32 + (ln >> 4) * 8; // K within part
      const float* p = wsrc + (part ? (size_t)GATES * HID : (size_t)0)
                            + (size_t)col * HID + k;
      h16x8 v;
#pragma unroll
      for (int e = 0; e < 8; ++e) v[e] = (h16)p[e];
      *(h16x8*)&wlds[(size_t)c * 8] = v;
    }
  }
  // combined bias (threads 0-255 use it)
  float bc[4];
  {
    const int j = tid & 7;
#pragma unroll
    for (int gg = 0; gg < 4; ++gg) {
      const int col = gg * HID + j0 + j;
      bc[gg] = bias[(size_t)layer * 2 * GATES + col] +
               bias[(size_t)layer * 2 * GATES + GATES + col];
    }
  }
  float creg2[2] = {0.f, 0.f};   // thread tid<256: c for i = 2p + (tid>>7)
  __syncthreads();

  const int own_base = layer * 128;
  const int oth_base = (1 - layer) * 128;
  const h16* bbI = wlds + (size_t)wave * 4096 + lane * 8;  // input-part B
  const h16* bbH = bbI + 32768;                            // hidden-part B
  const int kw = wave * 128 + l16 * 8;                     // per-wave K base

  for (int t = 0; t < S_LEN; ++t) {
    // ================= ONE merged wait =================
    {
      unsigned to = (unsigned)t;
      unsigned tx;
      if (layer == 0) {
        const int ct = t + 1 - RING_D;
        tx = (ct > 0) ? (unsigned)ct : 0u;
      } else {
        tx = (unsigned)(t + 1);
      }
      wave_poll_dual(flags, own_base, to, oth_base, tx, lane);
    }

    // ================= pointers =================
    const h16 *As, *Ah;
    h16* Hout;
    if (layer == 0) {
      As   = x16 + (size_t)t * BH;                            // plain cached
      Ah   = h0r + (size_t)((t + RING_D - 1) % RING_D) * BH;  // h0[t-1]
      Hout = h0r + (size_t)(t % RING_D) * BH;                 // h0[t]
    } else {
      As   = h0r + (size_t)(t % RING_D) * BH;                 // h0[t]
      Ah   = h1r + (size_t)((t + 1) & 1) * BH;                // h1[t-1]
      Hout = h1r + (size_t)(t & 1) * BH;                      // h1[t]
    }

    // ================= ONE 32-load burst =================
    h16x8 aS[4][4], aH[4][4];
    if (layer == 0) {
#pragma unroll
      for (int s = 0; s < 4; ++s)
#pragma unroll
        for (int i = 0; i < 4; ++i)
          aS[s][i] = *(const h16x8*)(As + (size_t)(i * 16 + l15) * HID +
                                     kw + s * 32);
    } else {
#pragma unroll
      for (int i = 0; i < 4; ++i) {
        const h16* ap = As + (size_t)(i * 16 + l15) * HID + kw;
        RLOAD(aS[0][i], ap, "0");
        RLOAD(aS[1][i], ap, "64");
        RLOAD(aS[2][i], ap, "128");
        RLOAD(aS[3][i], ap, "192");
      }
    }
#pragma unroll
    for (int i = 0; i < 4; ++i) {
      const h16* ap = Ah + (size_t)(i * 16 + l15) * HID + kw;
      RLOAD(aH[0][i], ap, "0");
      RLOAD(aH[1][i], ap, "64");
      RLOAD(aH[2][i], ap, "128");
      RLOAD(aH[3][i], ap, "192");
    }
    asm volatile("s_waitcnt vmcnt(0)" ::: "memory");
    __builtin_amdgcn_sched_barrier(0);

    // ================= 64 MFMA straight-line =================
    f32x4 acc[4][2];
#pragma unroll
    for (int i = 0; i < 4; ++i)
#pragma unroll
      for (int n2 = 0; n2 < 2; ++n2) acc[i][n2] = (f32x4)0.f;

#pragma unroll
    for (int s = 0; s < 4; ++s) {
      const h16x8 b0 = *(const h16x8*)(bbI + s * 512);
      const h16x8 b1 = *(const h16x8*)(bbI + 2048 + s * 512);
#pragma unroll
      for (int i = 0; i < 4; ++i) {
        acc[i][0] = __builtin_amdgcn_mfma_f32_16x16x32_f16(aS[s][i], b0, acc[i][0], 0, 0, 0);
        acc[i][1] = __builtin_amdgcn_mfma_f32_16x16x32_f16(aS[s][i], b1, acc[i][1], 0, 0, 0);
      }
    }
#pragma unroll
    for (int s = 0; s < 4; ++s) {
      const h16x8 b0 = *(const h16x8*)(bbH + s * 512);
      const h16x8 b1 = *(const h16x8*)(bbH + 2048 + s * 512);
#pragma unroll
      for (int i = 0; i < 4; ++i) {
        acc[i][0] = __builtin_amdgcn_mfma_f32_16x16x32_f16(aH[s][i], b0, acc[i][0], 0, 0, 0);
        acc[i][1] = __builtin_amdgcn_mfma_f32_16x16x32_f16(aH[s][i], b1, acc[i][1], 0, 0, 0);
      }
    }

    // ---- 8-way cross-wave reduce, 2 rounds of 2 m-tiles (4 syncthreads) ---
#pragma unroll
    for (int p = 0; p < 2; ++p) {
#pragma unroll
      for (int ii = 0; ii < 2; ++ii) {
        const int i = p * 2 + ii;
#pragma unroll
        for (int n2 = 0; n2 < 2; ++n2)
#pragma unroll
          for (int q = 0; q < 4; ++q) {
            const int r = l16 * 4 + q;                        // 0..15
            const int colS = (n2 * 16 + l15) ^ ((r & 7) << 2);
            plds[ii][wave][r][colS] = acc[i][n2][q];
          }
      }
      __syncthreads();
      if (tid < 256) {
        const int ii = tid >> 7, r = (tid >> 3) & 15, j = tid & 7;
        float gv[4];
#pragma unroll
        for (int gg = 0; gg < 4; ++gg) {
          const int colS = (gg * 8 + j) ^ ((r & 7) << 2);
          float s = bc[gg];
#pragma unroll
          for (int w = 0; w < 8; ++w) s += plds[ii][w][r][colS];
          gv[gg] = s;
        }
        const float ig = 1.f / (1.f + __expf(-gv[0]));
        const float fg = 1.f / (1.f + __expf(-gv[1]));
        const float gt = 1.f - 2.f / (__expf(2.f * gv[2]) + 1.f);
        const float og = 1.f / (1.f + __expf(-gv[3]));
        const float cn = fg * creg2[p] + ig * gt;
        creg2[p] = cn;
        const float th = 1.f - 2.f / (__expf(2.f * cn) + 1.f);
        union { h16 f; unsigned short u; } hb;
        hb.f = (h16)(og * th);
        const int row = (p * 2 + ii) * 16 + r;
        __hip_atomic_store(
            (unsigned short*)&Hout[(size_t)row * HID + j0 + j],
            hb.u, __ATOMIC_RELAXED, __HIP_MEMORY_SCOPE_AGENT);
      }
      __syncthreads();   // drains each wave's vmcnt: h-stores at L3
    }

    // ---- publish step completion ----
    if (tid == 0)
      __hip_atomic_store(&flags[wg * FLAG_STRIDE], (unsigned)(t + 1),
                         __ATOMIC_RELAXED, __HIP_MEMORY_SCOPE_AGENT);
  }
}

// ---------------------------------------------------------------------------
// out[m][cls] = h[m] . fc_w[cls] + fc_b[cls]. One wave per output.
// ---------------------------------------------------------------------------
__global__ __launch_bounds__(256)
void fc_kernel(const h16* __restrict__ h,
               const float* __restrict__ fw,
               const float* __restrict__ fb,
               float* __restrict__ out)
{
  const int gw = (blockIdx.x * blockDim.x + threadIdx.x) >> 6;
  const int lane = threadIdx.x & 63;
  if (gw >= BATCH * 10) return;
  const int m = gw / 10, cls = gw % 10;
  float s = 0.f;
  for (int k = lane; k < HID; k += 64)
    s += (float)h[(size_t)m * HID + k] * fw[(size_t)cls * HID + k];
#pragma unroll
  for (int off = 32; off; off >>= 1) s += __shfl_down(s, off);
  if (lane == 0) out[m * 10 + cls] = s + fb[cls];
}

// ---------------------------------------------------------------------------
extern "C" void kernel_launch(void* const* d_in, const int* in_sizes, int n_in,
                              void* d_out, int out_size, void* d_ws, size_t ws_size,
                              hipStream_t stream)
{
  const float* x      = (const float*)d_in[0];   // [256][64][1024]
  const float* weight = (const float*)d_in[1];   // [2][2][4096][1024]
  const float* bias   = (const float*)d_in[2];   // [2][2][4096]
  const float* fc_w   = (const float*)d_in[3];   // [10][1024]
  const float* fc_b   = (const float*)d_in[4];   // [10]
  float* out = (float*)d_out;                    // [64][10]

  auto align = [](size_t v) { return (v + 255) & ~(size_t)255; };
  const size_t flags_sz = (size_t)NBLK * FLAG_STRIDE * sizeof(unsigned);   // 32 KB
  const size_t x16_sz   = (size_t)S_LEN * BATCH * HID * sizeof(h16);       // 32 MB
  const size_t h0r_sz   = (size_t)RING_D * BATCH * HID * sizeof(h16);      // 512 KB
  const size_t h1r_sz   = (size_t)2 * BATCH * HID * sizeof(h16);           // 256 KB

  char* p = (char*)d_ws;
  unsigned* flags = (unsigned*)p; p += align(flags_sz);
  h16* x16 = (h16*)p; p += align(x16_sz);
  h16* h0r = (h16*)p; p += align(h0r_sz);
  h16* h1r = (h16*)p; p += align(h1r_sz);

  hipMemsetAsync(flags, 0, flags_sz, stream);
  hipMemsetAsync(h0r, 0, h0r_sz, stream);
  hipMemsetAsync(h1r, 0, h1r_sz, stream);

  xconv_kernel<<<dim3(2048), 256, 0, stream>>>(x, x16);

  lstm_persistent<<<dim3(NBLK), dim3(512), 0, stream>>>(
      x16, weight, bias, h0r, h1r, flags);

  // final h of top layer: t = 255 -> h1 ring slot 1
  fc_kernel<<<dim3((BATCH * 10 * 64) / 256), 256, 0, stream>>>(
      h1r + (size_t)BATCH * HID, fc_w, fc_b, out);
}

// Round 16
// 2411.298 us; speedup vs baseline: 1.2738x; 1.2738x over previous
//
#include <hip/hip_runtime.h>
#include <cstdint>
#include <cstddef>

#define S_LEN 256
#define BATCH 64
#define HID   1024
#define GATES 4096
#define NBLK  256
#define RING_D 4         // h0 ring depth

typedef _Float16 h16;
typedef _Float16 h16x8 __attribute__((ext_vector_type(8)));
typedef _Float16 h16x4 __attribute__((ext_vector_type(4)));
typedef float    f32x4 __attribute__((ext_vector_type(4)));

// ---------------------------------------------------------------------------
// x fp32 -> fp16 (one pass)
// ---------------------------------------------------------------------------
__global__ __launch_bounds__(256)
void xconv_kernel(const float* __restrict__ x, h16* __restrict__ x16)
{
  const int n4 = S_LEN * BATCH * HID / 4;
  const int stride = gridDim.x * 256;
  for (int i = blockIdx.x * 256 + threadIdx.x; i < n4; i += stride) {
    f32x4 v = ((const f32x4*)x)[i];
    h16x4 o;
    o[0] = (h16)v[0]; o[1] = (h16)v[1]; o[2] = (h16)v[2]; o[3] = (h16)v[3];
    ((h16x4*)x16)[i] = o;
  }
}

// ---------------------------------------------------------------------------
// Device-scope (sc1) 16B load: bypasses L1+L2, reads L3 coherence point.
// Issued without internal wait so batches pipeline; caller fences with
// vmcnt(0) + sched_barrier(0) before use (rule-18).
// ---------------------------------------------------------------------------
#define RLOAD(dst, ptr, OFFSTR)                                         \
  asm volatile("global_load_dwordx4 %0, %1, off offset:" OFFSTR " sc1"  \
               : "=&v"(dst) : "v"(ptr) : "memory")

// ---------------------------------------------------------------------------
// COMPACT epoch poll: group g's 128 blocks each own a u16 epoch in ONE 256B
// region (2 cache lines). A wave polls the whole group with a single dword
// load per lane (lane i checks epochs 2i, 2i+1). Total poll footprint per
// iteration: 2 lines (vs 128 padded lines before) -> ~64x less L3 request
// pressure. Publishers use global_store_short sc1 (distinct bytes, race-free,
// write-through to L3). Epochs <= 256 fit u16.
// ---------------------------------------------------------------------------
__device__ __forceinline__ void wave_poll_c(const unsigned* grp, unsigned tgt)
{
  const unsigned* p = grp + (threadIdx.x & 63);
  while (true) {
    const unsigned u = __hip_atomic_load(p, __ATOMIC_RELAXED,
                                         __HIP_MEMORY_SCOPE_AGENT);
    if ((u & 0xffffu) >= tgt && (u >> 16) >= tgt) break;
    __builtin_amdgcn_s_sleep(1);
  }
}

// ---------------------------------------------------------------------------
// Persistent 2-layer decoupled-pipeline LSTM (R14 structure + compact flags).
// 256 WGs x 512 thr. Group 0 = blocks 0..127 (layer 0), group 1 = layer 1.
// Per iteration t:
//   SHADOW : accI = input-half partials (x16[t] / h0[t]); L1 waves first
//            compact-poll L0 epochs >= t+1.
//   WAIT   : compact-poll own epochs >= t; L0 also polls L1 >= t+1-RING_D.
//   CRITICAL: load h_own[t-1] (16x16B sc1), 32 MFMAs on accI, 2-round 8-way
//            LDS reduce, activations, sc1 h stores, publish epoch t+1.
// LDS: 128KB weights + 32KB plds = exactly 160 KiB.
// No cache maintenance anywhere: mutable data all-sc1, immutable plain.
// ---------------------------------------------------------------------------
__global__ __launch_bounds__(512, 1)
void lstm_persistent(const h16* __restrict__ x16,
                     const float* __restrict__ weight,
                     const float* __restrict__ bias,
                     h16* __restrict__ h0r,
                     h16* __restrict__ h1r,
                     unsigned* __restrict__ ep)   // [2][64] uints = 2x256B
{
  __shared__ h16   wlds[65536];          // 128 KB
  __shared__ float plds[2][8][16][32];   // 32 KB

  const int wg    = blockIdx.x;
  const int layer = wg >> 7;
  const int j0    = (wg & 127) * 8;
  const int tid   = threadIdx.x;
  const int wave  = tid >> 6, lane = tid & 63;
  const int l15   = lane & 15, l16 = lane >> 4;
  const int BH    = BATCH * HID;

  // ---- one-time: pack weights fp32->fp16 into LDS ----
  // c = (((part*8 + w)*2 + n2)*4 + s)*64 + ln
  {
    const float* wsrc = weight + (size_t)layer * 2 * GATES * HID;
    for (int c = tid; c < 8192; c += 512) {
      const int ln = c & 63, s = (c >> 6) & 3, n2 = (c >> 8) & 1,
                w = (c >> 9) & 7, part = c >> 12;
      const int lc  = n2 * 16 + (ln & 15);              // local col 0..31
      const int col = (lc >> 3) * HID + j0 + (lc & 7);  // global gate col
      const int k   = w * 128 + s * 32 + (ln >> 4) * 8; // K within part
      const float* p = wsrc + (part ? (size_t)GATES * HID : (size_t)0)
                            + (size_t)col * HID + k;
      h16x8 v;
#pragma unroll
      for (int e = 0; e < 8; ++e) v[e] = (h16)p[e];
      *(h16x8*)&wlds[(size_t)c * 8] = v;
    }
  }
  // combined bias (threads 0-255 use it)
  float bc[4];
  {
    const int j = tid & 7;
#pragma unroll
    for (int gg = 0; gg < 4; ++gg) {
      const int col = gg * HID + j0 + j;
      bc[gg] = bias[(size_t)layer * 2 * GATES + col] +
               bias[(size_t)layer * 2 * GATES + GATES + col];
    }
  }
  float creg2[2] = {0.f, 0.f};   // thread tid<256: c for i = 2p + (tid>>7)
  __syncthreads();

  const unsigned* ep_own = ep + layer * 64;
  const unsigned* ep_oth = ep + (1 - layer) * 64;
  unsigned short* my_ep  = (unsigned short*)ep + (size_t)layer * 128 + (wg & 127);
  const h16* bbI = wlds + (size_t)wave * 4096 + lane * 8;  // input-part B
  const h16* bbH = bbI + 32768;                            // hidden-part B
  const int kw = wave * 128 + l16 * 8;                     // per-wave K base

  for (int t = 0; t < S_LEN; ++t) {
    // ================= SHADOW: input-half partials for step t ==============
    const h16* As;
    if (layer == 0) {
      As = x16 + (size_t)t * BH;                       // always ready
    } else {
      wave_poll_c(ep_oth, (unsigned)(t + 1));          // h0[t] ready
      As = h0r + (size_t)(t % RING_D) * BH;
    }

    f32x4 accI[4][2];
#pragma unroll
    for (int i = 0; i < 4; ++i)
#pragma unroll
      for (int n2 = 0; n2 < 2; ++n2) accI[i][n2] = (f32x4)0.f;

#pragma unroll
    for (int sc = 0; sc < 2; ++sc) {
      h16x8 aS[2][4];
      if (layer == 0) {
#pragma unroll
        for (int ss = 0; ss < 2; ++ss)
#pragma unroll
          for (int i = 0; i < 4; ++i)
            aS[ss][i] = *(const h16x8*)(As + (size_t)(i * 16 + l15) * HID +
                                        kw + (sc * 2 + ss) * 32);
      } else {
#pragma unroll
        for (int i = 0; i < 4; ++i) {
          const h16* ap = As + (size_t)(i * 16 + l15) * HID + kw + sc * 64;
          RLOAD(aS[0][i], ap, "0");
          RLOAD(aS[1][i], ap, "64");
        }
        asm volatile("s_waitcnt vmcnt(0)" ::: "memory");
        __builtin_amdgcn_sched_barrier(0);
      }
#pragma unroll
      for (int ss = 0; ss < 2; ++ss) {
        const int s = sc * 2 + ss;
        const h16x8 b0 = *(const h16x8*)(bbI + s * 512);
        const h16x8 b1 = *(const h16x8*)(bbI + 2048 + s * 512);
#pragma unroll
        for (int i = 0; i < 4; ++i) {
          accI[i][0] = __builtin_amdgcn_mfma_f32_16x16x32_f16(aS[ss][i], b0, accI[i][0], 0, 0, 0);
          accI[i][1] = __builtin_amdgcn_mfma_f32_16x16x32_f16(aS[ss][i], b1, accI[i][1], 0, 0, 0);
        }
      }
    }

    // ================= WAIT (compact): own @ t; L0 ring safety ============
    if (t) wave_poll_c(ep_own, (unsigned)t);
    if (layer == 0) {
      const int ct = t + 1 - RING_D;
      if (ct > 0) wave_poll_c(ep_oth, (unsigned)ct);
    }

    // ================= CRITICAL: hidden-half + reduce + publish ===========
    const h16* Ah;                    // h_own[t-1]
    h16* Hout;                        // h_own[t]
    if (layer == 0) {
      Ah   = h0r + (size_t)((t + RING_D - 1) % RING_D) * BH;
      Hout = h0r + (size_t)(t % RING_D) * BH;
    } else {
      Ah   = h1r + (size_t)((t + 1) & 1) * BH;
      Hout = h1r + (size_t)(t & 1) * BH;
    }

    h16x8 aH[4][4];
#pragma unroll
    for (int i = 0; i < 4; ++i) {
      const h16* ap = Ah + (size_t)(i * 16 + l15) * HID + kw;
      RLOAD(aH[i][0], ap, "0");
      RLOAD(aH[i][1], ap, "64");
      RLOAD(aH[i][2], ap, "128");
      RLOAD(aH[i][3], ap, "192");
    }
    asm volatile("s_waitcnt vmcnt(0)" ::: "memory");
    __builtin_amdgcn_sched_barrier(0);

    f32x4 acc[4][2];
#pragma unroll
    for (int i = 0; i < 4; ++i)
#pragma unroll
      for (int n2 = 0; n2 < 2; ++n2) acc[i][n2] = accI[i][n2];

#pragma unroll
    for (int s = 0; s < 4; ++s) {
      const h16x8 b0 = *(const h16x8*)(bbH + s * 512);
      const h16x8 b1 = *(const h16x8*)(bbH + 2048 + s * 512);
#pragma unroll
      for (int i = 0; i < 4; ++i) {
        acc[i][0] = __builtin_amdgcn_mfma_f32_16x16x32_f16(aH[i][s], b0, acc[i][0], 0, 0, 0);
        acc[i][1] = __builtin_amdgcn_mfma_f32_16x16x32_f16(aH[i][s], b1, acc[i][1], 0, 0, 0);
      }
    }

    // ---- 8-way cross-wave reduce, 2 rounds of 2 m-tiles (4 syncthreads) ---
#pragma unroll
    for (int p = 0; p < 2; ++p) {
#pragma unroll
      for (int ii = 0; ii < 2; ++ii) {
        const int i = p * 2 + ii;
#pragma unroll
        for (int n2 = 0; n2 < 2; ++n2)
#pragma unroll
          for (int q = 0; q < 4; ++q) {
            const int r = l16 * 4 + q;                        // 0..15
            const int colS = (n2 * 16 + l15) ^ ((r & 7) << 2);
            plds[ii][wave][r][colS] = acc[i][n2][q];
          }
      }
      __syncthreads();
      if (tid < 256) {
        const int ii = tid >> 7, r = (tid >> 3) & 15, j = tid & 7;
        float gv[4];
#pragma unroll
        for (int gg = 0; gg < 4; ++gg) {
          const int colS = (gg * 8 + j) ^ ((r & 7) << 2);
          float s = bc[gg];
#pragma unroll
          for (int w = 0; w < 8; ++w) s += plds[ii][w][r][colS];
          gv[gg] = s;
        }
        const float ig = 1.f / (1.f + __expf(-gv[0]));
        const float fg = 1.f / (1.f + __expf(-gv[1]));
        const float gt = 1.f - 2.f / (__expf(2.f * gv[2]) + 1.f);
        const float og = 1.f / (1.f + __expf(-gv[3]));
        const float cn = fg * creg2[p] + ig * gt;
        creg2[p] = cn;
        const float th = 1.f - 2.f / (__expf(2.f * cn) + 1.f);
        union { h16 f; unsigned short u; } hb;
        hb.f = (h16)(og * th);
        const int row = (p * 2 + ii) * 16 + r;
        __hip_atomic_store(
            (unsigned short*)&Hout[(size_t)row * HID + j0 + j],
            hb.u, __ATOMIC_RELAXED, __HIP_MEMORY_SCOPE_AGENT);
      }
      __syncthreads();   // drains each wave's vmcnt: h-stores at L3
    }

    // ---- publish step completion: u16 epoch into the compact line ----
    if (tid == 0)
      asm volatile("global_store_short %0, %1, off sc1"
                   :: "v"(my_ep), "v"(t + 1) : "memory");
  }
}

// ---------------------------------------------------------------------------
// out[m][cls] = h[m] . fc_w[cls] + fc_b[cls]. One wave per output.
// ---------------------------------------------------------------------------
__global__ __launch_bounds__(256)
void fc_kernel(const h16* __restrict__ h,
               const float* __restrict__ fw,
               const float* __restrict__ fb,
               float* __restrict__ out)
{
  const int gw = (blockIdx.x * blockDim.x + threadIdx.x) >> 6;
  const int lane = threadIdx.x & 63;
  if (gw >= BATCH * 10) return;
  const int m = gw / 10, cls = gw % 10;
  float s = 0.f;
  for (int k = lane; k < HID; k += 64)
    s += (float)h[(size_t)m * HID + k] * fw[(size_t)cls * HID + k];
#pragma unroll
  for (int off = 32; off; off >>= 1) s += __shfl_down(s, off);
  if (lane == 0) out[m * 10 + cls] = s + fb[cls];
}

// ---------------------------------------------------------------------------
extern "C" void kernel_launch(void* const* d_in, const int* in_sizes, int n_in,
                              void* d_out, int out_size, void* d_ws, size_t ws_size,
                              hipStream_t stream)
{
  const float* x      = (const float*)d_in[0];   // [256][64][1024]
  const float* weight = (const float*)d_in[1];   // [2][2][4096][1024]
  const float* bias   = (const float*)d_in[2];   // [2][2][4096]
  const float* fc_w   = (const float*)d_in[3];   // [10][1024]
  const float* fc_b   = (const float*)d_in[4];   // [10]
  float* out = (float*)d_out;                    // [64][10]

  auto align = [](size_t v) { return (v + 255) & ~(size_t)255; };
  const size_t ep_sz   = 512;                                              // 2x256B
  const size_t x16_sz  = (size_t)S_LEN * BATCH * HID * sizeof(h16);        // 32 MB
  const size_t h0r_sz  = (size_t)RING_D * BATCH * HID * sizeof(h16);       // 512 KB
  const size_t h1r_sz  = (size_t)2 * BATCH * HID * sizeof(h16);            // 256 KB

  char* p = (char*)d_ws;
  unsigned* ep = (unsigned*)p; p += align(ep_sz);
  h16* x16 = (h16*)p; p += align(x16_sz);
  h16* h0r = (h16*)p; p += align(h0r_sz);
  h16* h1r = (h16*)p; p += align(h1r_sz);

  hipMemsetAsync(ep, 0, ep_sz, stream);
  hipMemsetAsync(h0r, 0, h0r_sz, stream);
  hipMemsetAsync(h1r, 0, h1r_sz, stream);

  xconv_kernel<<<dim3(2048), 256, 0, stream>>>(x, x16);

  lstm_persistent<<<dim3(NBLK), dim3(512), 0, stream>>>(
      x16, weight, bias, h0r, h1r, ep);

  // final h of top layer: t = 255 -> h1 ring slot 1
  fc_kernel<<<dim3((BATCH * 10 * 64) / 256), 256, 0, stream>>>(
      h1r + (size_t)BATCH * HID, fc_w, fc_b, out);
}